// Round 20
// baseline (138.774 us; speedup 1.0000x reference)
//
#include <hip/hip_runtime.h>
#include <hip/hip_bf16.h>

constexpr int BTOT = 524288;
constexpr int NN   = 64;
constexpr int H    = 32;
constexpr int V    = 256;

typedef __attribute__((ext_vector_type(4))) float f32x4;
typedef __attribute__((ext_vector_type(4))) int   int4v;
typedef __attribute__((ext_vector_type(8))) short short8;

union FragU { int4v i; short8 s; };

__device__ __forceinline__ float fast_rcp(float x){ return __builtin_amdgcn_rcpf(x); }
__device__ __forceinline__ float fast_tanh(float x){
    float e = __expf(2.0f * x);
    return 1.0f - 2.0f * fast_rcp(e + 1.0f);
}
__device__ __forceinline__ int pkbf(float lo, float hi){
    union { __hip_bfloat162 h2; int i; } u;
    u.h2.x = __float2bfloat16(lo);
    u.h2.y = __float2bfloat16(hi);
    return u.i;
}
__device__ __forceinline__ void nt_store4(float* p, f32x4 v){
    __builtin_nontemporal_store(v, reinterpret_cast<f32x4*>(p));
}
__device__ __forceinline__ void nt_store1(float* p, float v){
    __builtin_nontemporal_store(v, p);
}

// ---------------- precomputed fragment tables (module globals) ----------------
__device__ __attribute__((aligned(16))) int   g_Wfrag [6*2*64*4];
__device__ __attribute__((aligned(16))) int   g_Kfrag [4*64*4];
__device__ __attribute__((aligned(16))) int   g_Vfrag [2*2*64*4];
__device__ __attribute__((aligned(16))) int   g_Wsfrag[16*64*4];
__device__ __attribute__((aligned(16))) float g_biasd [6*64*8];
__device__ __attribute__((aligned(16))) float g_gated [64*8];
__device__ __attribute__((aligned(16))) float g_wad   [64*8];
__device__ __attribute__((aligned(16))) float g_wid   [64*24];

__global__ void precompute(const float* __restrict__ other_hidden,
                           const float* __restrict__ mem_gate,
                           const float* __restrict__ Wk, const float* __restrict__ bk,
                           const float* __restrict__ Wv, const float* __restrict__ bv,
                           const float* __restrict__ Wm, const float* __restrict__ bm,
                           const float* __restrict__ Wq, const float* __restrict__ bq,
                           const float* __restrict__ W1, const float* __restrict__ b1,
                           const float* __restrict__ W2, const float* __restrict__ b2,
                           const float* __restrict__ W3, const float* __restrict__ b3,
                           const float* __restrict__ W4, const float* __restrict__ b4,
                           const float* __restrict__ Wa, const float* __restrict__ Wi,
                           const float* __restrict__ Ws)
{
    __shared__ float Kst[64][32];
    __shared__ float Vst[64][32];
    __shared__ float gateS[32];
    const int t = threadIdx.x;

    if (t < 32) gateS[t] = fast_rcp(1.0f + __expf(-mem_gate[t]));
    {   // K = other@Wk+bk, V = other@Wv+bv
        int n = t >> 2, c = (t & 3) * 8;
        float ak[8], av[8];
        #pragma unroll
        for (int i = 0; i < 8; ++i){ ak[i] = bk[c+i]; av[i] = bv[c+i]; }
        #pragma unroll
        for (int j = 0; j < H; ++j){
            float x = other_hidden[n*H + j];
            #pragma unroll
            for (int i = 0; i < 8; ++i){
                ak[i] = fmaf(x, Wk[j*H + c + i], ak[i]);
                av[i] = fmaf(x, Wv[j*H + c + i], av[i]);
            }
        }
        #pragma unroll
        for (int i = 0; i < 8; ++i){ Kst[n][c+i] = ak[i]; Vst[n][c+i] = av[i]; }
    }
    __syncthreads();

    #pragma unroll
    for (int w = 0; w < 6; ++w){
        const float* W = (w==0)?Wm : (w==1)?Wq : (w==2)?W1 : (w==3)?W2 : (w==4)?W3 : W4;
        for (int e = t; e < 128; e += 256){
            int mt = e >> 6, l = e & 63, la = l & 15, g = l >> 4;
            int m = mt*16 + la;
            int base = ((w*2 + mt)*64 + l)*4;
            #pragma unroll
            for (int j = 0; j < 4; ++j){
                int k0 = g*8 + 2*j;
                g_Wfrag[base + j] = pkbf(W[k0*H + m], W[(k0+1)*H + m]);
            }
        }
    }
    #pragma unroll
    for (int w = 0; w < 6; ++w){
        const float* bp_ = (w==0)?bm : (w==1)?bq : (w==2)?b1 : (w==3)?b2 : (w==4)?b3 : b4;
        for (int e = t; e < 512; e += 256){
            int l = e >> 3, idx = e & 7, mt = idx >> 2, r = idx & 3;
            int F = mt*16 + ((l>>4)&3)*4 + r;
            g_biasd[(w*64 + l)*8 + idx] = bp_[F];
        }
    }
    {
        int e = t;
        int mt = e >> 6, l = e & 63, la = l & 15, g = l >> 4;
        int n = mt*16 + la;
        #pragma unroll
        for (int j = 0; j < 4; ++j){
            int k0 = g*8 + 2*j;
            g_Kfrag[e*4 + j] = pkbf(Kst[n][k0], Kst[n][k0+1]);
        }
    }
    {
        int e = t;
        int mt = e >> 7, kt = (e >> 6) & 1, l = e & 63, la = l & 15, g = l >> 4;
        int m = mt*16 + la;
        #pragma unroll
        for (int j = 0; j < 4; ++j){
            int n0 = kt*32 + g*8 + 2*j;
            g_Vfrag[e*4 + j] = pkbf(Vst[n0][m], Vst[n0+1][m]);
        }
    }
    for (int e = t; e < 1024; e += 256){
        int mt = e >> 6, l = e & 63, la = l & 15, g = l >> 4;
        int m = mt*16 + la;
        #pragma unroll
        for (int j = 0; j < 4; ++j){
            int k0 = g*8 + 2*j;
            g_Wsfrag[e*4 + j] = pkbf(Ws[k0*V + m], Ws[(k0+1)*V + m]);
        }
    }
    for (int e = t; e < 512; e += 256){
        int l = e >> 3, idx = e & 7;
        int F = (idx>>2)*16 + ((l>>4)&3)*4 + (idx&3);
        g_gated[e] = gateS[F];
        g_wad[e]   = Wa[F];
    }
    for (int e = t; e < 1536; e += 256){
        int l = e / 24, m2 = e % 24, fidx = m2 / 3, j = m2 % 3;
        int F = (fidx>>2)*16 + ((l>>4)&3)*4 + (fidx&3);
        g_wid[e] = Wi[F*3 + j];
    }
}

// ---- D->B fragment conversion ----
__device__ __forceinline__ FragU d2b(f32x4 m0, f32x4 m1, int idxA, int idxB, bool glo){
    int p0a = pkbf(m0[0], m0[1]);
    int p1a = pkbf(m0[2], m0[3]);
    int p0b = pkbf(m1[0], m1[1]);
    int p1b = pkbf(m1[2], m1[3]);
    int tA0  = __builtin_amdgcn_ds_bpermute(idxA, p0a);
    int tA0b = __builtin_amdgcn_ds_bpermute(idxA, p0b);
    int tA1  = __builtin_amdgcn_ds_bpermute(idxA, p1a);
    int tA1b = __builtin_amdgcn_ds_bpermute(idxA, p1b);
    int tB0  = __builtin_amdgcn_ds_bpermute(idxB, p0a);
    int tB0b = __builtin_amdgcn_ds_bpermute(idxB, p0b);
    int tB1  = __builtin_amdgcn_ds_bpermute(idxB, p1a);
    int tB1b = __builtin_amdgcn_ds_bpermute(idxB, p1b);
    FragU r;
    r.i = int4v{ glo ? tA0 : tA0b, glo ? tA1 : tA1b,
                 glo ? tB0 : tB0b, glo ? tB1 : tB1b };
    return r;
}

__device__ __forceinline__ float bred_sum(float v, int bx16, int bx32){
    v += __int_as_float(__builtin_amdgcn_ds_bpermute(bx16, __float_as_int(v)));
    v += __int_as_float(__builtin_amdgcn_ds_bpermute(bx32, __float_as_int(v)));
    return v;
}
__device__ __forceinline__ float bred_max(float v, int bx16, int bx32){
    v = fmaxf(v, __int_as_float(__builtin_amdgcn_ds_bpermute(bx16, __float_as_int(v))));
    v = fmaxf(v, __int_as_float(__builtin_amdgcn_ds_bpermute(bx32, __float_as_int(v))));
    return v;
}
__device__ __forceinline__ f32x4 tanh4(f32x4 v){
    f32x4 r;
    r[0] = fast_tanh(v[0]); r[1] = fast_tanh(v[1]);
    r[2] = fast_tanh(v[2]); r[3] = fast_tanh(v[3]);
    return r;
}

#define MFMA(a, b, c) __builtin_amdgcn_mfma_f32_16x16x32_bf16((a), (b), (c), 0, 0, 0)

// TPB=2 + NT stores, 3 blocks/CU: two 128-apart tiles per wave; all tile1
// input loads issued before tile0's first store (in-order vmcnt FIFO), so no
// wait in tile1 drains tile0's burst. Store phase reads only LDS.
__global__ __launch_bounds__(256, 3) void social_main(
    const int*   __restrict__ symbol,
    const float* __restrict__ prev_hidden,
    const float* __restrict__ emb,
    const float* __restrict__ bs,
    const float* __restrict__ ba,
    const float* __restrict__ bi,
    float* __restrict__ out)
{
    const int tid = threadIdx.x;
    const int wv = tid >> 6, l = tid & 63;
    const int la = l & 15, g = l >> 4;
    const bool glo = (g < 2);
    const int idxA = (((g & 1) << 5) + la) << 2;
    const int idxB = idxA + 64;
    const int bx16 = (l ^ 16) << 2;
    const int bx32 = (l ^ 32) << 2;
    const int base = blockIdx.x * 256 + wv * 32;

    __shared__ f32x4 stgAll[4][256];    // 16 KB swizzled staging
    __shared__ int4v sSF[1024];         // 16 KB Ws^T frags (lgkmcnt reads)
    __shared__ float bsS[256];          //  1 KB symbol-head bias
    f32x4* buf = stgAll[wv];

    {
        const int4v* q4 = reinterpret_cast<const int4v*>(g_Wsfrag);
        for (int i = tid; i < 1024; i += 256) sSF[i] = q4[i];
        bsS[tid] = bs[tid];
    }
    __syncthreads();

    float* out_action = out;
    float* out_sym    = out + (size_t)BTOT;
    float* out_int    = out + (size_t)BTOT * (1 + V);
    float* out_h      = out + (size_t)BTOT * (1 + V + 3);

    const int4v* WF = reinterpret_cast<const int4v*>(g_Wfrag);
    const int4v* KF = reinterpret_cast<const int4v*>(g_Kfrag);
    const int4v* VF = reinterpret_cast<const int4v*>(g_Vfrag);
    const f32x4 zero4 = {0.f, 0.f, 0.f, 0.f};

    // ---- pipeline slots (statically indexed after full unroll) ----
    FragU phbA[2][2];
    f32x4 emA[2][2][2];   // [slot][mt][nt]
    int symN0, symN1;

    {   // prologue: tile0 pv+sym+emb, tile1 sym — no stores yet, cheap waits
        #pragma unroll
        for (int nt = 0; nt < 2; ++nt){
            const f32x4* p = reinterpret_cast<const f32x4*>(
                prev_hidden + (size_t)(base + nt*16 + la) * H + g*8);
            f32x4 v0 = p[0], v1 = p[1];
            phbA[0][nt].i = int4v{ pkbf(v0[0],v0[1]), pkbf(v0[2],v0[3]),
                                   pkbf(v1[0],v1[1]), pkbf(v1[2],v1[3]) };
        }
        int s0 = symbol[base + la], s1 = symbol[base + 16 + la];
        symN0 = symbol[base + 128 + la];
        symN1 = symbol[base + 128 + 16 + la];
        #pragma unroll
        for (int mt = 0; mt < 2; ++mt)
        #pragma unroll
        for (int nt = 0; nt < 2; ++nt)
            emA[0][mt][nt] = *reinterpret_cast<const f32x4*>(
                emb + (size_t)(nt ? s1 : s0)*H + mt*16 + g*4);
    }

    #pragma unroll
    for (int t = 0; t < 2; ++t){
        const int A0 = base + t*128;

        // ---- issue next tile's prev_hidden loads at body top (t==0) ----
        f32x4 pvr[2][2];
        if (t == 0){
            #pragma unroll
            for (int nt = 0; nt < 2; ++nt){
                const f32x4* p = reinterpret_cast<const f32x4*>(
                    prev_hidden + (size_t)(base + 128 + nt*16 + la) * H + g*8);
                pvr[nt][0] = p[0]; pvr[nt][1] = p[1];
            }
        }

        // ---- mem = tanh(ph@Wm + bm); h = e*(1-gate) + mem*gate ----
        f32x4 h_[2][2];
        {
            f32x4 bias0 = *reinterpret_cast<const f32x4*>(g_biasd + l*8);
            f32x4 bias1 = *reinterpret_cast<const f32x4*>(g_biasd + l*8 + 4);
            f32x4 m_[2][2];
            #pragma unroll
            for (int mt = 0; mt < 2; ++mt){
                FragU af; af.i = WF[(0*2 + mt)*64 + l];
                #pragma unroll
                for (int nt = 0; nt < 2; ++nt)
                    m_[mt][nt] = MFMA(af.s, phbA[t][nt].s, mt ? bias1 : bias0);
            }
            f32x4 gt0 = *reinterpret_cast<const f32x4*>(g_gated + l*8);
            f32x4 gt1 = *reinterpret_cast<const f32x4*>(g_gated + l*8 + 4);
            #pragma unroll
            for (int mt = 0; mt < 2; ++mt)
            #pragma unroll
            for (int nt = 0; nt < 2; ++nt){
                #pragma unroll
                for (int r = 0; r < 4; ++r){
                    float gv = mt ? gt1[r] : gt0[r];
                    h_[mt][nt][r] = emA[t][mt][nt][r]*(1.0f - gv)
                                  + fast_tanh(m_[mt][nt][r])*gv;
                }
            }
        }

        // ---- q = h@Wq + bq ----
        f32x4 q_[2][2];
        {
            f32x4 bias0 = *reinterpret_cast<const f32x4*>(g_biasd + 512 + l*8);
            f32x4 bias1 = *reinterpret_cast<const f32x4*>(g_biasd + 512 + l*8 + 4);
            FragU hb0[2] = { d2b(h_[0][0], h_[1][0], idxA, idxB, glo),
                             d2b(h_[0][1], h_[1][1], idxA, idxB, glo) };
            #pragma unroll
            for (int mt = 0; mt < 2; ++mt){
                FragU af; af.i = WF[(1*2 + mt)*64 + l];
                #pragma unroll
                for (int nt = 0; nt < 2; ++nt)
                    q_[mt][nt] = MFMA(af.s, hb0[nt].s, mt ? bias1 : bias0);
            }
        }

        // ---- scores S[n][agent] = K @ q^T ----
        f32x4 s_[4][2];
        {
            FragU qb[2] = { d2b(q_[0][0], q_[1][0], idxA, idxB, glo),
                            d2b(q_[0][1], q_[1][1], idxA, idxB, glo) };
            #pragma unroll
            for (int mt = 0; mt < 4; ++mt){
                FragU af; af.i = KF[mt*64 + l];
                #pragma unroll
                for (int nt = 0; nt < 2; ++nt)
                    s_[mt][nt] = MFMA(af.s, qb[nt].s, zero4);
            }
        }

        // ---- finish tile1 prefetch (t==0): emb gather + phb pack, all
        // BEFORE any store of this tile ----
        if (t == 0){
            #pragma unroll
            for (int mt = 0; mt < 2; ++mt)
            #pragma unroll
            for (int nt = 0; nt < 2; ++nt)
                emA[1][mt][nt] = *reinterpret_cast<const f32x4*>(
                    emb + (size_t)(nt ? symN1 : symN0)*H + mt*16 + g*4);
            #pragma unroll
            for (int nt = 0; nt < 2; ++nt)
                phbA[1][nt].i = int4v{ pkbf(pvr[nt][0][0], pvr[nt][0][1]),
                                       pkbf(pvr[nt][0][2], pvr[nt][0][3]),
                                       pkbf(pvr[nt][1][0], pvr[nt][1][1]),
                                       pkbf(pvr[nt][1][2], pvr[nt][1][3]) };
        }

        // ---- softmax over 64 neighbors ----
        const float INVS = 0.17677669529663687f;  // 1/sqrt(32)
        float coef[2];
        #pragma unroll
        for (int nt = 0; nt < 2; ++nt){
            float mx = s_[0][nt][0];
            #pragma unroll
            for (int mt = 0; mt < 4; ++mt)
            #pragma unroll
            for (int r = 0; r < 4; ++r) mx = fmaxf(mx, s_[mt][nt][r]);
            mx = bred_max(mx, bx16, bx32);
            float den = 0.f;
            #pragma unroll
            for (int mt = 0; mt < 4; ++mt)
            #pragma unroll
            for (int r = 0; r < 4; ++r){
                float w = __expf((s_[mt][nt][r] - mx) * INVS);
                s_[mt][nt][r] = w;
                den += w;
            }
            den = bred_sum(den, bx16, bx32);
            coef[nt] = 0.3f * fast_rcp(den);
        }

        // ---- attnout = V^T @ w ; h += 0.3 * attnout / den ----
        {
            FragU wb[2][2];
            #pragma unroll
            for (int kt = 0; kt < 2; ++kt)
            #pragma unroll
            for (int nt = 0; nt < 2; ++nt)
                wb[kt][nt] = d2b(s_[2*kt][nt], s_[2*kt+1][nt], idxA, idxB, glo);
            #pragma unroll
            for (int mt = 0; mt < 2; ++mt){
                FragU vf0, vf1;
                vf0.i = VF[(mt*2 + 0)*64 + l];
                vf1.i = VF[(mt*2 + 1)*64 + l];
                #pragma unroll
                for (int nt = 0; nt < 2; ++nt){
                    f32x4 acc = MFMA(vf0.s, wb[0][nt].s, zero4);
                    acc = MFMA(vf1.s, wb[1][nt].s, acc);
                    h_[mt][nt] += acc * coef[nt];
                }
            }
        }

        // ---- 4 gated-residual tanh MLP blocks ----
        #pragma unroll 1
        for (int blk = 0; blk < 4; ++blk){
            f32x4 bias0 = *reinterpret_cast<const f32x4*>(g_biasd + (2+blk)*512 + l*8);
            f32x4 bias1 = *reinterpret_cast<const f32x4*>(g_biasd + (2+blk)*512 + l*8 + 4);
            FragU hb1[2] = { d2b(h_[0][0], h_[1][0], idxA, idxB, glo),
                             d2b(h_[0][1], h_[1][1], idxA, idxB, glo) };
            #pragma unroll
            for (int mt = 0; mt < 2; ++mt){
                FragU af; af.i = WF[((2+blk)*2 + mt)*64 + l];
                #pragma unroll
                for (int nt = 0; nt < 2; ++nt){
                    f32x4 tv = MFMA(af.s, hb1[nt].s, mt ? bias1 : bias0);
                    h_[mt][nt] += 0.3f * tanh4(tv);
                }
            }
        }

        // ---- hb frags for symbol head ----
        FragU hb[2] = { d2b(h_[0][0], h_[1][0], idxA, idxB, glo),
                        d2b(h_[0][1], h_[1][1], idxA, idxB, glo) };

        // ---- action head ----
        {
            union { f32x4 v[2]; float s[8]; } wa;
            wa.v[0] = *reinterpret_cast<const f32x4*>(g_wad + l*8);
            wa.v[1] = *reinterpret_cast<const f32x4*>(g_wad + l*8 + 4);
            float ba0 = ba[0];
            float act[2];
            #pragma unroll
            for (int nt = 0; nt < 2; ++nt){
                float acc = 0.f;
                #pragma unroll
                for (int mt = 0; mt < 2; ++mt)
                #pragma unroll
                for (int r = 0; r < 4; ++r)
                    acc = fmaf(h_[mt][nt][r], wa.s[mt*4 + r], acc);
                acc = bred_sum(acc, bx16, bx32);
                act[nt] = fast_tanh(acc + ba0);
            }
            if (l < 16){
                nt_store1(out_action + A0 + la,      act[0]);
                nt_store1(out_action + A0 + 16 + la, act[1]);
            }
        }

        // ---- intent head ----
        {
            union { f32x4 v[6]; float s[24]; } wi;
            #pragma unroll
            for (int k = 0; k < 6; ++k)
                wi.v[k] = *(reinterpret_cast<const f32x4*>(g_wid + l*24) + k);
            float bi0 = bi[0], bi1 = bi[1], bi2 = bi[2];
            #pragma unroll
            for (int nt = 0; nt < 2; ++nt){
                float i0 = 0.f, i1 = 0.f, i2 = 0.f;
                #pragma unroll
                for (int mt = 0; mt < 2; ++mt)
                #pragma unroll
                for (int r = 0; r < 4; ++r){
                    float hv = h_[mt][nt][r];
                    int bidx = (mt*4 + r)*3;
                    i0 = fmaf(hv, wi.s[bidx + 0], i0);
                    i1 = fmaf(hv, wi.s[bidx + 1], i1);
                    i2 = fmaf(hv, wi.s[bidx + 2], i2);
                }
                i0 = bred_sum(i0, bx16, bx32) + bi0;
                i1 = bred_sum(i1, bx16, bx32) + bi1;
                i2 = bred_sum(i2, bx16, bx32) + bi2;
                if (l < 16){
                    size_t a = (size_t)(A0 + nt*16 + la);
                    nt_store1(out_int + a*3 + 0, i0);
                    nt_store1(out_int + a*3 + 1, i1);
                    nt_store1(out_int + a*3 + 2, i2);
                }
            }
        }

        // ---- h output: XOR-swizzled b128 stage -> full-line NT stores ----
        {
            #pragma unroll
            for (int nt = 0; nt < 2; ++nt)
            #pragma unroll
            for (int mt = 0; mt < 2; ++mt){
                int a = nt*16 + la;
                int blk = mt*4 + g;
                buf[a*8 + (blk ^ (a & 7))] = h_[mt][nt];
            }
            int rdA = l >> 3, rdB = l & 7;
            #pragma unroll
            for (int j = 0; j < 4; ++j){
                int a = j*8 + rdA;
                f32x4 ov = buf[a*8 + (rdB ^ (a & 7))];
                nt_store4(out_h + (size_t)(A0 + a)*H + rdB*4, ov);
            }
        }

        // ---- symbol head: b128 swizzled stage, full-line NT stores; SF +
        // bias from LDS -> no vmcnt-ordered loads in the store phase ----
        {
            int rdA = l >> 3, rdB = l & 7;
            #pragma unroll
            for (int mtp = 0; mtp < 8; ++mtp){
                #pragma unroll
                for (int hh = 0; hh < 2; ++hh){
                    int mt = mtp*2 + hh;
                    FragU af; af.i = sSF[mt*64 + l];
                    f32x4 o0 = MFMA(af.s, hb[0].s, zero4);
                    f32x4 o1 = MFMA(af.s, hb[1].s, zero4);
                    int blk = hh*4 + g;
                    int a0 = la, a1 = 16 + la;
                    buf[a0*8 + (blk ^ (a0 & 7))] = o0;
                    buf[a1*8 + (blk ^ (a1 & 7))] = o1;
                }
                f32x4 bv = *reinterpret_cast<const f32x4*>(bsS + mtp*32 + rdB*4);
                #pragma unroll
                for (int j = 0; j < 4; ++j){
                    int a = j*8 + rdA;
                    f32x4 ov = buf[a*8 + (rdB ^ (a & 7))];
                    ov += bv;
                    nt_store4(out_sym + (size_t)(A0 + a)*V + mtp*32 + rdB*4, ov);
                }
            }
        }
    }
}

extern "C" void kernel_launch(void* const* d_in, const int* in_sizes, int n_in,
                              void* d_out, int out_size, void* d_ws, size_t ws_size,
                              hipStream_t stream)
{
    const int*   symbol       = (const int*)  d_in[0];
    const float* other_hidden = (const float*)d_in[1];
    const float* prev_hidden  = (const float*)d_in[2];
    const float* emb          = (const float*)d_in[3];
    const float* mem_gate     = (const float*)d_in[4];
    const float* Wm  = (const float*)d_in[5];  const float* bm = (const float*)d_in[6];
    const float* Wq  = (const float*)d_in[7];  const float* bq = (const float*)d_in[8];
    const float* Wk  = (const float*)d_in[9];  const float* bk = (const float*)d_in[10];
    const float* Wv  = (const float*)d_in[11]; const float* bv = (const float*)d_in[12];
    const float* W1  = (const float*)d_in[13]; const float* b1 = (const float*)d_in[14];
    const float* W2  = (const float*)d_in[15]; const float* b2 = (const float*)d_in[16];
    const float* W3  = (const float*)d_in[17]; const float* b3 = (const float*)d_in[18];
    const float* W4  = (const float*)d_in[19]; const float* b4 = (const float*)d_in[20];
    const float* Wa  = (const float*)d_in[21]; const float* ba = (const float*)d_in[22];
    const float* Wsm = (const float*)d_in[23]; const float* bs = (const float*)d_in[24];
    const float* Wi  = (const float*)d_in[25]; const float* bi = (const float*)d_in[26];

    precompute<<<1, 256, 0, stream>>>(other_hidden, mem_gate, Wk, bk, Wv, bv,
                                      Wm, bm, Wq, bq, W1, b1, W2, b2, W3, b3, W4, b4,
                                      Wa, Wi, Wsm);

    social_main<<<BTOT / 256, 256, 0, stream>>>(symbol, prev_hidden, emb, bs, ba, bi,
                                                (float*)d_out);
}

// Round 21
// 132.750 us; speedup vs baseline: 1.0454x; 1.0454x over previous
//
#include <hip/hip_runtime.h>
#include <hip/hip_bf16.h>

constexpr int BTOT = 524288;
constexpr int NN   = 64;
constexpr int H    = 32;
constexpr int V    = 256;

typedef __attribute__((ext_vector_type(4))) float f32x4;
typedef __attribute__((ext_vector_type(4))) int   int4v;
typedef __attribute__((ext_vector_type(8))) short short8;

union FragU { int4v i; short8 s; };

__device__ __forceinline__ float fast_rcp(float x){ return __builtin_amdgcn_rcpf(x); }
__device__ __forceinline__ float fast_tanh(float x){
    float e = __expf(2.0f * x);
    return 1.0f - 2.0f * fast_rcp(e + 1.0f);
}
__device__ __forceinline__ int pkbf(float lo, float hi){
    union { __hip_bfloat162 h2; int i; } u;
    u.h2.x = __float2bfloat16(lo);
    u.h2.y = __float2bfloat16(hi);
    return u.i;
}
__device__ __forceinline__ void nt_store4(float* p, f32x4 v){
    __builtin_nontemporal_store(v, reinterpret_cast<f32x4*>(p));
}
__device__ __forceinline__ void nt_store1(float* p, float v){
    __builtin_nontemporal_store(v, p);
}

// ---------------- precomputed fragment tables (module globals) ----------------
__device__ __attribute__((aligned(16))) int   g_Wfrag [6*2*64*4];
__device__ __attribute__((aligned(16))) int   g_Kfrag [4*64*4];
__device__ __attribute__((aligned(16))) int   g_Vfrag [2*2*64*4];
__device__ __attribute__((aligned(16))) int   g_Wsfrag[16*64*4];
__device__ __attribute__((aligned(16))) float g_biasd [6*64*8];
__device__ __attribute__((aligned(16))) float g_gated [64*8];
__device__ __attribute__((aligned(16))) float g_wad   [64*8];
__device__ __attribute__((aligned(16))) float g_wid   [64*24];

__global__ void precompute(const float* __restrict__ other_hidden,
                           const float* __restrict__ mem_gate,
                           const float* __restrict__ Wk, const float* __restrict__ bk,
                           const float* __restrict__ Wv, const float* __restrict__ bv,
                           const float* __restrict__ Wm, const float* __restrict__ bm,
                           const float* __restrict__ Wq, const float* __restrict__ bq,
                           const float* __restrict__ W1, const float* __restrict__ b1,
                           const float* __restrict__ W2, const float* __restrict__ b2,
                           const float* __restrict__ W3, const float* __restrict__ b3,
                           const float* __restrict__ W4, const float* __restrict__ b4,
                           const float* __restrict__ Wa, const float* __restrict__ Wi,
                           const float* __restrict__ Ws)
{
    __shared__ float Kst[64][32];
    __shared__ float Vst[64][32];
    __shared__ float gateS[32];
    const int t = threadIdx.x;

    if (t < 32) gateS[t] = fast_rcp(1.0f + __expf(-mem_gate[t]));
    {   // K = other@Wk+bk, V = other@Wv+bv
        int n = t >> 2, c = (t & 3) * 8;
        float ak[8], av[8];
        #pragma unroll
        for (int i = 0; i < 8; ++i){ ak[i] = bk[c+i]; av[i] = bv[c+i]; }
        #pragma unroll
        for (int j = 0; j < H; ++j){
            float x = other_hidden[n*H + j];
            #pragma unroll
            for (int i = 0; i < 8; ++i){
                ak[i] = fmaf(x, Wk[j*H + c + i], ak[i]);
                av[i] = fmaf(x, Wv[j*H + c + i], av[i]);
            }
        }
        #pragma unroll
        for (int i = 0; i < 8; ++i){ Kst[n][c+i] = ak[i]; Vst[n][c+i] = av[i]; }
    }
    __syncthreads();

    #pragma unroll
    for (int w = 0; w < 6; ++w){
        const float* W = (w==0)?Wm : (w==1)?Wq : (w==2)?W1 : (w==3)?W2 : (w==4)?W3 : W4;
        for (int e = t; e < 128; e += 256){
            int mt = e >> 6, l = e & 63, la = l & 15, g = l >> 4;
            int m = mt*16 + la;
            int base = ((w*2 + mt)*64 + l)*4;
            #pragma unroll
            for (int j = 0; j < 4; ++j){
                int k0 = g*8 + 2*j;
                g_Wfrag[base + j] = pkbf(W[k0*H + m], W[(k0+1)*H + m]);
            }
        }
    }
    #pragma unroll
    for (int w = 0; w < 6; ++w){
        const float* bp_ = (w==0)?bm : (w==1)?bq : (w==2)?b1 : (w==3)?b2 : (w==4)?b3 : b4;
        for (int e = t; e < 512; e += 256){
            int l = e >> 3, idx = e & 7, mt = idx >> 2, r = idx & 3;
            int F = mt*16 + ((l>>4)&3)*4 + r;
            g_biasd[(w*64 + l)*8 + idx] = bp_[F];
        }
    }
    {
        int e = t;
        int mt = e >> 6, l = e & 63, la = l & 15, g = l >> 4;
        int n = mt*16 + la;
        #pragma unroll
        for (int j = 0; j < 4; ++j){
            int k0 = g*8 + 2*j;
            g_Kfrag[e*4 + j] = pkbf(Kst[n][k0], Kst[n][k0+1]);
        }
    }
    {
        int e = t;
        int mt = e >> 7, kt = (e >> 6) & 1, l = e & 63, la = l & 15, g = l >> 4;
        int m = mt*16 + la;
        #pragma unroll
        for (int j = 0; j < 4; ++j){
            int n0 = kt*32 + g*8 + 2*j;
            g_Vfrag[e*4 + j] = pkbf(Vst[n0][m], Vst[n0+1][m]);
        }
    }
    for (int e = t; e < 1024; e += 256){
        int mt = e >> 6, l = e & 63, la = l & 15, g = l >> 4;
        int m = mt*16 + la;
        #pragma unroll
        for (int j = 0; j < 4; ++j){
            int k0 = g*8 + 2*j;
            g_Wsfrag[e*4 + j] = pkbf(Ws[k0*V + m], Ws[(k0+1)*V + m]);
        }
    }
    for (int e = t; e < 512; e += 256){
        int l = e >> 3, idx = e & 7;
        int F = (idx>>2)*16 + ((l>>4)&3)*4 + (idx&3);
        g_gated[e] = gateS[F];
        g_wad[e]   = Wa[F];
    }
    for (int e = t; e < 1536; e += 256){
        int l = e / 24, m2 = e % 24, fidx = m2 / 3, j = m2 % 3;
        int F = (fidx>>2)*16 + ((l>>4)&3)*4 + (fidx&3);
        g_wid[e] = Wi[F*3 + j];
    }
}

// ---- D->B fragment conversion ----
__device__ __forceinline__ FragU d2b(f32x4 m0, f32x4 m1, int idxA, int idxB, bool glo){
    int p0a = pkbf(m0[0], m0[1]);
    int p1a = pkbf(m0[2], m0[3]);
    int p0b = pkbf(m1[0], m1[1]);
    int p1b = pkbf(m1[2], m1[3]);
    int tA0  = __builtin_amdgcn_ds_bpermute(idxA, p0a);
    int tA0b = __builtin_amdgcn_ds_bpermute(idxA, p0b);
    int tA1  = __builtin_amdgcn_ds_bpermute(idxA, p1a);
    int tA1b = __builtin_amdgcn_ds_bpermute(idxA, p1b);
    int tB0  = __builtin_amdgcn_ds_bpermute(idxB, p0a);
    int tB0b = __builtin_amdgcn_ds_bpermute(idxB, p0b);
    int tB1  = __builtin_amdgcn_ds_bpermute(idxB, p1a);
    int tB1b = __builtin_amdgcn_ds_bpermute(idxB, p1b);
    FragU r;
    r.i = int4v{ glo ? tA0 : tA0b, glo ? tA1 : tA1b,
                 glo ? tB0 : tB0b, glo ? tB1 : tB1b };
    return r;
}

__device__ __forceinline__ float bred_sum(float v, int bx16, int bx32){
    v += __int_as_float(__builtin_amdgcn_ds_bpermute(bx16, __float_as_int(v)));
    v += __int_as_float(__builtin_amdgcn_ds_bpermute(bx32, __float_as_int(v)));
    return v;
}
__device__ __forceinline__ float bred_max(float v, int bx16, int bx32){
    v = fmaxf(v, __int_as_float(__builtin_amdgcn_ds_bpermute(bx16, __float_as_int(v))));
    v = fmaxf(v, __int_as_float(__builtin_amdgcn_ds_bpermute(bx32, __float_as_int(v))));
    return v;
}
__device__ __forceinline__ f32x4 tanh4(f32x4 v){
    f32x4 r;
    r[0] = fast_tanh(v[0]); r[1] = fast_tanh(v[1]);
    r[2] = fast_tanh(v[2]); r[3] = fast_tanh(v[3]);
    return r;
}

#define MFMA(a, b, c) __builtin_amdgcn_mfma_f32_16x16x32_bf16((a), (b), (c), 0, 0, 0)

// TPB=2 + NT stores: two 128-apart tiles per wave; all tile1 input loads are
// issued before tile0's first store (in-order vmcnt FIFO discipline), so no
// wait in tile1 drains tile0's burst. Store phase reads only LDS. Halves the
// number of block retires (each retire waits vmcnt(0) on the final burst).
__global__ __launch_bounds__(256, 2) void social_main(
    const int*   __restrict__ symbol,
    const float* __restrict__ prev_hidden,
    const float* __restrict__ emb,
    const float* __restrict__ bs,
    const float* __restrict__ ba,
    const float* __restrict__ bi,
    float* __restrict__ out)
{
    const int tid = threadIdx.x;
    const int wv = tid >> 6, l = tid & 63;
    const int la = l & 15, g = l >> 4;
    const bool glo = (g < 2);
    const int idxA = (((g & 1) << 5) + la) << 2;
    const int idxB = idxA + 64;
    const int bx16 = (l ^ 16) << 2;
    const int bx32 = (l ^ 32) << 2;
    const int base = blockIdx.x * 256 + wv * 32;

    __shared__ f32x4 stgAll[4][256];    // 16 KB swizzled staging
    __shared__ int4v sSF[1024];         // 16 KB Ws^T frags (lgkmcnt reads)
    __shared__ float bsS[256];          //  1 KB symbol-head bias
    f32x4* buf = stgAll[wv];

    {
        const int4v* q4 = reinterpret_cast<const int4v*>(g_Wsfrag);
        for (int i = tid; i < 1024; i += 256) sSF[i] = q4[i];
        bsS[tid] = bs[tid];
    }
    __syncthreads();

    float* out_action = out;
    float* out_sym    = out + (size_t)BTOT;
    float* out_int    = out + (size_t)BTOT * (1 + V);
    float* out_h      = out + (size_t)BTOT * (1 + V + 3);

    const int4v* WF = reinterpret_cast<const int4v*>(g_Wfrag);
    const int4v* KF = reinterpret_cast<const int4v*>(g_Kfrag);
    const int4v* VF = reinterpret_cast<const int4v*>(g_Vfrag);
    const f32x4 zero4 = {0.f, 0.f, 0.f, 0.f};

    // ---- pipeline slots (statically indexed after full unroll) ----
    FragU phbA[2][2];
    f32x4 emA[2][2][2];   // [slot][mt][nt]
    int symN0, symN1;

    {   // prologue: tile0 pv+sym+emb, tile1 sym — no stores yet, cheap waits
        #pragma unroll
        for (int nt = 0; nt < 2; ++nt){
            const f32x4* p = reinterpret_cast<const f32x4*>(
                prev_hidden + (size_t)(base + nt*16 + la) * H + g*8);
            f32x4 v0 = p[0], v1 = p[1];
            phbA[0][nt].i = int4v{ pkbf(v0[0],v0[1]), pkbf(v0[2],v0[3]),
                                   pkbf(v1[0],v1[1]), pkbf(v1[2],v1[3]) };
        }
        int s0 = symbol[base + la], s1 = symbol[base + 16 + la];
        symN0 = symbol[base + 128 + la];
        symN1 = symbol[base + 128 + 16 + la];
        #pragma unroll
        for (int mt = 0; mt < 2; ++mt)
        #pragma unroll
        for (int nt = 0; nt < 2; ++nt)
            emA[0][mt][nt] = *reinterpret_cast<const f32x4*>(
                emb + (size_t)(nt ? s1 : s0)*H + mt*16 + g*4);
    }

    #pragma unroll
    for (int t = 0; t < 2; ++t){
        const int A0 = base + t*128;

        // ---- issue next tile's prev_hidden loads at body top (t==0) ----
        f32x4 pvr[2][2];
        if (t == 0){
            #pragma unroll
            for (int nt = 0; nt < 2; ++nt){
                const f32x4* p = reinterpret_cast<const f32x4*>(
                    prev_hidden + (size_t)(base + 128 + nt*16 + la) * H + g*8);
                pvr[nt][0] = p[0]; pvr[nt][1] = p[1];
            }
        }

        // ---- mem = tanh(ph@Wm + bm); h = e*(1-gate) + mem*gate ----
        f32x4 h_[2][2];
        {
            f32x4 bias0 = *reinterpret_cast<const f32x4*>(g_biasd + l*8);
            f32x4 bias1 = *reinterpret_cast<const f32x4*>(g_biasd + l*8 + 4);
            f32x4 m_[2][2];
            #pragma unroll
            for (int mt = 0; mt < 2; ++mt){
                FragU af; af.i = WF[(0*2 + mt)*64 + l];
                #pragma unroll
                for (int nt = 0; nt < 2; ++nt)
                    m_[mt][nt] = MFMA(af.s, phbA[t][nt].s, mt ? bias1 : bias0);
            }
            f32x4 gt0 = *reinterpret_cast<const f32x4*>(g_gated + l*8);
            f32x4 gt1 = *reinterpret_cast<const f32x4*>(g_gated + l*8 + 4);
            #pragma unroll
            for (int mt = 0; mt < 2; ++mt)
            #pragma unroll
            for (int nt = 0; nt < 2; ++nt){
                #pragma unroll
                for (int r = 0; r < 4; ++r){
                    float gv = mt ? gt1[r] : gt0[r];
                    h_[mt][nt][r] = emA[t][mt][nt][r]*(1.0f - gv)
                                  + fast_tanh(m_[mt][nt][r])*gv;
                }
            }
        }

        // ---- q = h@Wq + bq ----
        f32x4 q_[2][2];
        {
            f32x4 bias0 = *reinterpret_cast<const f32x4*>(g_biasd + 512 + l*8);
            f32x4 bias1 = *reinterpret_cast<const f32x4*>(g_biasd + 512 + l*8 + 4);
            FragU hb0[2] = { d2b(h_[0][0], h_[1][0], idxA, idxB, glo),
                             d2b(h_[0][1], h_[1][1], idxA, idxB, glo) };
            #pragma unroll
            for (int mt = 0; mt < 2; ++mt){
                FragU af; af.i = WF[(1*2 + mt)*64 + l];
                #pragma unroll
                for (int nt = 0; nt < 2; ++nt)
                    q_[mt][nt] = MFMA(af.s, hb0[nt].s, mt ? bias1 : bias0);
            }
        }

        // ---- scores S[n][agent] = K @ q^T ----
        f32x4 s_[4][2];
        {
            FragU qb[2] = { d2b(q_[0][0], q_[1][0], idxA, idxB, glo),
                            d2b(q_[0][1], q_[1][1], idxA, idxB, glo) };
            #pragma unroll
            for (int mt = 0; mt < 4; ++mt){
                FragU af; af.i = KF[mt*64 + l];
                #pragma unroll
                for (int nt = 0; nt < 2; ++nt)
                    s_[mt][nt] = MFMA(af.s, qb[nt].s, zero4);
            }
        }

        // ---- finish tile1 prefetch (t==0): emb gather + phb pack, all
        // BEFORE any store of this tile ----
        if (t == 0){
            #pragma unroll
            for (int mt = 0; mt < 2; ++mt)
            #pragma unroll
            for (int nt = 0; nt < 2; ++nt)
                emA[1][mt][nt] = *reinterpret_cast<const f32x4*>(
                    emb + (size_t)(nt ? symN1 : symN0)*H + mt*16 + g*4);
            #pragma unroll
            for (int nt = 0; nt < 2; ++nt)
                phbA[1][nt].i = int4v{ pkbf(pvr[nt][0][0], pvr[nt][0][1]),
                                       pkbf(pvr[nt][0][2], pvr[nt][0][3]),
                                       pkbf(pvr[nt][1][0], pvr[nt][1][1]),
                                       pkbf(pvr[nt][1][2], pvr[nt][1][3]) };
        }

        // ---- softmax over 64 neighbors ----
        const float INVS = 0.17677669529663687f;  // 1/sqrt(32)
        float coef[2];
        #pragma unroll
        for (int nt = 0; nt < 2; ++nt){
            float mx = s_[0][nt][0];
            #pragma unroll
            for (int mt = 0; mt < 4; ++mt)
            #pragma unroll
            for (int r = 0; r < 4; ++r) mx = fmaxf(mx, s_[mt][nt][r]);
            mx = bred_max(mx, bx16, bx32);
            float den = 0.f;
            #pragma unroll
            for (int mt = 0; mt < 4; ++mt)
            #pragma unroll
            for (int r = 0; r < 4; ++r){
                float w = __expf((s_[mt][nt][r] - mx) * INVS);
                s_[mt][nt][r] = w;
                den += w;
            }
            den = bred_sum(den, bx16, bx32);
            coef[nt] = 0.3f * fast_rcp(den);
        }

        // ---- attnout = V^T @ w ; h += 0.3 * attnout / den ----
        {
            FragU wb[2][2];
            #pragma unroll
            for (int kt = 0; kt < 2; ++kt)
            #pragma unroll
            for (int nt = 0; nt < 2; ++nt)
                wb[kt][nt] = d2b(s_[2*kt][nt], s_[2*kt+1][nt], idxA, idxB, glo);
            #pragma unroll
            for (int mt = 0; mt < 2; ++mt){
                FragU vf0, vf1;
                vf0.i = VF[(mt*2 + 0)*64 + l];
                vf1.i = VF[(mt*2 + 1)*64 + l];
                #pragma unroll
                for (int nt = 0; nt < 2; ++nt){
                    f32x4 acc = MFMA(vf0.s, wb[0][nt].s, zero4);
                    acc = MFMA(vf1.s, wb[1][nt].s, acc);
                    h_[mt][nt] += acc * coef[nt];
                }
            }
        }

        // ---- 4 gated-residual tanh MLP blocks ----
        #pragma unroll 1
        for (int blk = 0; blk < 4; ++blk){
            f32x4 bias0 = *reinterpret_cast<const f32x4*>(g_biasd + (2+blk)*512 + l*8);
            f32x4 bias1 = *reinterpret_cast<const f32x4*>(g_biasd + (2+blk)*512 + l*8 + 4);
            FragU hb1[2] = { d2b(h_[0][0], h_[1][0], idxA, idxB, glo),
                             d2b(h_[0][1], h_[1][1], idxA, idxB, glo) };
            #pragma unroll
            for (int mt = 0; mt < 2; ++mt){
                FragU af; af.i = WF[((2+blk)*2 + mt)*64 + l];
                #pragma unroll
                for (int nt = 0; nt < 2; ++nt){
                    f32x4 tv = MFMA(af.s, hb1[nt].s, mt ? bias1 : bias0);
                    h_[mt][nt] += 0.3f * tanh4(tv);
                }
            }
        }

        // ---- hb frags for symbol head ----
        FragU hb[2] = { d2b(h_[0][0], h_[1][0], idxA, idxB, glo),
                        d2b(h_[0][1], h_[1][1], idxA, idxB, glo) };

        // ---- action head ----
        {
            union { f32x4 v[2]; float s[8]; } wa;
            wa.v[0] = *reinterpret_cast<const f32x4*>(g_wad + l*8);
            wa.v[1] = *reinterpret_cast<const f32x4*>(g_wad + l*8 + 4);
            float ba0 = ba[0];
            float act[2];
            #pragma unroll
            for (int nt = 0; nt < 2; ++nt){
                float acc = 0.f;
                #pragma unroll
                for (int mt = 0; mt < 2; ++mt)
                #pragma unroll
                for (int r = 0; r < 4; ++r)
                    acc = fmaf(h_[mt][nt][r], wa.s[mt*4 + r], acc);
                acc = bred_sum(acc, bx16, bx32);
                act[nt] = fast_tanh(acc + ba0);
            }
            if (l < 16){
                nt_store1(out_action + A0 + la,      act[0]);
                nt_store1(out_action + A0 + 16 + la, act[1]);
            }
        }

        // ---- intent head ----
        {
            union { f32x4 v[6]; float s[24]; } wi;
            #pragma unroll
            for (int k = 0; k < 6; ++k)
                wi.v[k] = *(reinterpret_cast<const f32x4*>(g_wid + l*24) + k);
            float bi0 = bi[0], bi1 = bi[1], bi2 = bi[2];
            #pragma unroll
            for (int nt = 0; nt < 2; ++nt){
                float i0 = 0.f, i1 = 0.f, i2 = 0.f;
                #pragma unroll
                for (int mt = 0; mt < 2; ++mt)
                #pragma unroll
                for (int r = 0; r < 4; ++r){
                    float hv = h_[mt][nt][r];
                    int bidx = (mt*4 + r)*3;
                    i0 = fmaf(hv, wi.s[bidx + 0], i0);
                    i1 = fmaf(hv, wi.s[bidx + 1], i1);
                    i2 = fmaf(hv, wi.s[bidx + 2], i2);
                }
                i0 = bred_sum(i0, bx16, bx32) + bi0;
                i1 = bred_sum(i1, bx16, bx32) + bi1;
                i2 = bred_sum(i2, bx16, bx32) + bi2;
                if (l < 16){
                    size_t a = (size_t)(A0 + nt*16 + la);
                    nt_store1(out_int + a*3 + 0, i0);
                    nt_store1(out_int + a*3 + 1, i1);
                    nt_store1(out_int + a*3 + 2, i2);
                }
            }
        }

        // ---- h output: XOR-swizzled b128 stage -> full-line NT stores ----
        {
            #pragma unroll
            for (int nt = 0; nt < 2; ++nt)
            #pragma unroll
            for (int mt = 0; mt < 2; ++mt){
                int a = nt*16 + la;
                int blk = mt*4 + g;
                buf[a*8 + (blk ^ (a & 7))] = h_[mt][nt];
            }
            int rdA = l >> 3, rdB = l & 7;
            #pragma unroll
            for (int j = 0; j < 4; ++j){
                int a = j*8 + rdA;
                f32x4 ov = buf[a*8 + (rdB ^ (a & 7))];
                nt_store4(out_h + (size_t)(A0 + a)*H + rdB*4, ov);
            }
        }

        // ---- symbol head: b128 swizzled stage, full-line NT stores; SF +
        // bias from LDS -> no vmcnt-ordered loads in the store phase ----
        {
            int rdA = l >> 3, rdB = l & 7;
            #pragma unroll
            for (int mtp = 0; mtp < 8; ++mtp){
                #pragma unroll
                for (int hh = 0; hh < 2; ++hh){
                    int mt = mtp*2 + hh;
                    FragU af; af.i = sSF[mt*64 + l];
                    f32x4 o0 = MFMA(af.s, hb[0].s, zero4);
                    f32x4 o1 = MFMA(af.s, hb[1].s, zero4);
                    int blk = hh*4 + g;
                    int a0 = la, a1 = 16 + la;
                    buf[a0*8 + (blk ^ (a0 & 7))] = o0;
                    buf[a1*8 + (blk ^ (a1 & 7))] = o1;
                }
                f32x4 bv = *reinterpret_cast<const f32x4*>(bsS + mtp*32 + rdB*4);
                #pragma unroll
                for (int j = 0; j < 4; ++j){
                    int a = j*8 + rdA;
                    f32x4 ov = buf[a*8 + (rdB ^ (a & 7))];
                    ov += bv;
                    nt_store4(out_sym + (size_t)(A0 + a)*V + mtp*32 + rdB*4, ov);
                }
            }
        }
    }
}

extern "C" void kernel_launch(void* const* d_in, const int* in_sizes, int n_in,
                              void* d_out, int out_size, void* d_ws, size_t ws_size,
                              hipStream_t stream)
{
    const int*   symbol       = (const int*)  d_in[0];
    const float* other_hidden = (const float*)d_in[1];
    const float* prev_hidden  = (const float*)d_in[2];
    const float* emb          = (const float*)d_in[3];
    const float* mem_gate     = (const float*)d_in[4];
    const float* Wm  = (const float*)d_in[5];  const float* bm = (const float*)d_in[6];
    const float* Wq  = (const float*)d_in[7];  const float* bq = (const float*)d_in[8];
    const float* Wk  = (const float*)d_in[9];  const float* bk = (const float*)d_in[10];
    const float* Wv  = (const float*)d_in[11]; const float* bv = (const float*)d_in[12];
    const float* W1  = (const float*)d_in[13]; const float* b1 = (const float*)d_in[14];
    const float* W2  = (const float*)d_in[15]; const float* b2 = (const float*)d_in[16];
    const float* W3  = (const float*)d_in[17]; const float* b3 = (const float*)d_in[18];
    const float* W4  = (const float*)d_in[19]; const float* b4 = (const float*)d_in[20];
    const float* Wa  = (const float*)d_in[21]; const float* ba = (const float*)d_in[22];
    const float* Wsm = (const float*)d_in[23]; const float* bs = (const float*)d_in[24];
    const float* Wi  = (const float*)d_in[25]; const float* bi = (const float*)d_in[26];

    precompute<<<1, 256, 0, stream>>>(other_hidden, mem_gate, Wk, bk, Wv, bv,
                                      Wm, bm, Wq, bq, W1, b1, W2, b2, W3, b3, W4, b4,
                                      Wa, Wi, Wsm);

    social_main<<<BTOT / 256, 256, 0, stream>>>(symbol, prev_hidden, emb, bs, ba, bi,
                                                (float*)d_out);
}